// Round 8
// baseline (5840.595 us; speedup 1.0000x reference)
//
#include <hip/hip_runtime.h>
#include <stdint.h>

#define H_DIM   1024
#define G3      3072
#define EMB     50
#define TSTEPS  100
#define NB      4096
#define NLABEL  15

typedef __bf16 bf16x8 __attribute__((ext_vector_type(8)));
typedef float  f32x4  __attribute__((ext_vector_type(4)));
typedef int    i32x4  __attribute__((ext_vector_type(4)));

__device__ inline uint16_t f2bf(float f) {
  uint32_t u = __builtin_bit_cast(uint32_t, f);
  u += 0x7FFFu + ((u >> 16) & 1u);   // round-to-nearest-even
  return (uint16_t)(u >> 16);
}

__device__ inline void gld16(const void* g, void* l) {
  __builtin_amdgcn_global_load_lds(
      (const __attribute__((address_space(1))) uint32_t*)g,
      (__attribute__((address_space(3))) uint32_t*)l, 16, 0, 0);
}

// counted vmcnt + sched fence (rule #18: MFMA can hoist past bare asm waits)
#define VM(n) do { asm volatile("s_waitcnt vmcnt(" #n ")" ::: "memory"); \
                   __builtin_amdgcn_sched_barrier(0); } while (0)
#define LGKM0() do { asm volatile("s_waitcnt lgkmcnt(0)" ::: "memory"); \
                     __builtin_amdgcn_sched_barrier(0); } while (0)
#define BARF() do { __builtin_amdgcn_s_barrier(); \
                    asm volatile("" ::: "memory"); } while (0)
// async global->reg 16B load; dst reg reserved until later MFMA use
#define GLDB(dst, addr, OFF) \
  asm volatile("global_load_dwordx4 %0, %1, off offset:" OFF \
               : "=&v"(dst) : "v"(addr) : "memory")

// ---------------- prep kernels ----------------

__global__ __launch_bounds__(256) void prep_recT(const float* __restrict__ rec,
                                                 uint16_t* __restrict__ recT) {
  __shared__ uint16_t st[64][72];
  const int n0 = blockIdx.x * 64;
  const int k0 = blockIdx.y * 64;
  const int tid = threadIdx.x;
#pragma unroll
  for (int i = 0; i < 16; ++i) {
    int idx = tid + i * 256;
    int r = idx >> 6;
    int c = idx & 63;
    st[c][r] = f2bf(rec[(size_t)(k0 + r) * G3 + n0 + c]);
  }
  __syncthreads();
#pragma unroll
  for (int i = 0; i < 16; ++i) {
    int idx = tid + i * 256;
    int r = idx >> 6;
    int c = idx & 63;
    recT[(size_t)(n0 + r) * H_DIM + k0 + c] = st[r][c];
  }
}

__global__ __launch_bounds__(256) void prep_kerT(const float* __restrict__ ker,
                                                 uint16_t* __restrict__ kerT) {
  int n = blockIdx.x * 4 + (threadIdx.x >> 6);
  int k = threadIdx.x & 63;
  float v = (k < EMB) ? ker[(size_t)k * G3 + n] : 0.f;
  kerT[(size_t)n * 64 + k] = f2bf(v);
}

__global__ __launch_bounds__(256) void prep_embt(const int* __restrict__ x,
                                                 const float* __restrict__ tab,
                                                 uint16_t* __restrict__ embt) {
  int idx = blockIdx.x * 256 + threadIdx.x;
  int g = idx >> 5;
  int p = idx & 31;
  int t = g >> 12;
  int b = g & 4095;
  int row = x[b * TSTEPS + t];
  float2 v;
  if (p < 25) v = *reinterpret_cast<const float2*>(tab + (size_t)row * EMB + 2 * p);
  else { v.x = 0.f; v.y = 0.f; }
  uint32_t packed = (uint32_t)f2bf(v.x) | ((uint32_t)f2bf(v.y) << 16);
  *reinterpret_cast<uint32_t*>(embt + (size_t)g * 64 + 2 * p) = packed;
}

// ---------------- fused GRU step ----------------
// grid 512 (2 blocks/CU), block 256 (4 waves, 2x2). Tile: 128 rows x 64 cols,
// 3 gates. B-frags: DIRECT global->VGPR (asm dwordx4, per-gate single-buffer,
// counted vmcnt). A: gld16->LDS (32 KB, XOR-swizzled), ONE barrier per K-tile.
__global__ __launch_bounds__(256, 2) void gru_step_kernel(
    const uint16_t* __restrict__ hb_prev,   // [4096][1024] bf16
    float* __restrict__ hf,                 // [4096][1024] f32 (in-place)
    uint16_t* __restrict__ hb_next,         // [4096][1024] bf16
    const uint16_t* __restrict__ recT,      // [3072][1024] bf16
    const uint16_t* __restrict__ kerT,      // [3072][64]   bf16
    const uint16_t* __restrict__ embt,      // [4096][64]   bf16 (this step)
    const float* __restrict__ bias_i,       // [3072]
    const float* __restrict__ bias_r) {     // [3072]
  __shared__ __align__(16) uint16_t sA2[2][128 * 64];     // 32 KB

  const int tid  = threadIdx.x;
  const int lane = tid & 63;
  const int wid  = tid >> 6;     // 0..3
  const int wm   = wid >> 1;     // wave row 0..1 (64 rows each)
  const int wn   = wid & 1;      // wave col 0..1 (32 cols each)
  const int bid  = blockIdx.x;
  // XCD remap: xk = bid%8 -> XCD; each XCD: 8 rowblks x 8 colblks
  const int xk = bid & 7, slot = bid >> 3;          // slot 0..63
  const int rowblk = (xk >> 1) * 8 + (slot >> 3);   // 0..31
  const int colblk = (xk & 1) * 8 + (slot & 7);     // 0..15
  const int r0 = rowblk * 128;
  const int j0 = colblk * 64;

  const int swz8 = 8 * ((lane & 7) ^ (lane >> 3));

  bf16x8 af[4][2];               // A-frags (single-buffered)
  i32x4  bfv[3][2][2];           // B-frags [gate][nf][ks] (single-buffered)
  f32x4 accZ[4][2], accR[4][2], accH[4][2], accX[4][2];
#pragma unroll
  for (int m = 0; m < 4; ++m)
#pragma unroll
    for (int n = 0; n < 2; ++n) {
      accZ[m][n] = (f32x4){0.f, 0.f, 0.f, 0.f};
      accR[m][n] = (f32x4){0.f, 0.f, 0.f, 0.f};
      accH[m][n] = (f32x4){0.f, 0.f, 0.f, 0.f};
      accX[m][n] = (f32x4){0.f, 0.f, 0.f, 0.f};
    }

  // B base pointers per (gate, nf): row = g*1024 + j0 + wn*32 + nf*16 + (lane&15),
  // col chunk (lane>>4)*8; advanced +64 elems (one K-tile) per tile.
  const uint16_t* bB[3][2];
#pragma unroll
  for (int g = 0; g < 3; ++g)
#pragma unroll
    for (int nf = 0; nf < 2; ++nf)
      bB[g][nf] = recT +
          (size_t)(g * H_DIM + j0 + wn * 32 + nf * 16 + (lane & 15)) * H_DIM +
          (lane >> 4) * 8;

  // stage A-tile for tile t (4 gld16/thread, 16 KB)
  auto stageA = [&](int t) {
    const int abuf = t & 1;
#pragma unroll
    for (int i = 0; i < 4; ++i) {
      int chunk = wid * 4 + i;                // 0..15
      int row = chunk * 8 + (lane >> 3);
      const uint16_t* src = (t < 16)
          ? hb_prev + (size_t)(r0 + row) * H_DIM + t * 64 + swz8
          : embt + (size_t)(r0 + row) * 64 + swz8;
      gld16(src, &sA2[abuf][(chunk * 64 + lane) * 8]);
    }
  };
  // read A fragments for tile t (8 ds_read_b128)
  auto readA = [&](int t) {
    const int abuf = t & 1;
#pragma unroll
    for (int ks = 0; ks < 2; ++ks) {
      const int colswz = (ks * 32 + (lane >> 4) * 8) ^ ((lane & 7) << 3);
#pragma unroll
      for (int mf = 0; mf < 4; ++mf)
        af[mf][ks] = *reinterpret_cast<const bf16x8*>(
            &sA2[abuf][(wm * 64 + mf * 16 + (lane & 15)) * 64 + colswz]);
    }
  };

// issue 4 B-loads of gate g (FIFO order: nf0ks0, nf0ks1, nf1ks0, nf1ks1)
#define ISSUE_BG(g, P0, P1) do { \
    GLDB(bfv[g][0][0], P0, "0");  GLDB(bfv[g][0][1], P0, "64"); \
    GLDB(bfv[g][1][0], P1, "0");  GLDB(bfv[g][1][1], P1, "64"); \
  } while (0)
// 16 MFMA of gate g into ACC
#define MFG(g, ACC) do { \
    __builtin_amdgcn_s_setprio(1); \
    _Pragma("unroll") for (int ks = 0; ks < 2; ++ks) \
    _Pragma("unroll") for (int nf = 0; nf < 2; ++nf) \
    _Pragma("unroll") for (int mf = 0; mf < 4; ++mf) \
      ACC[mf][nf] = __builtin_amdgcn_mfma_f32_16x16x32_bf16( \
          af[mf][ks], __builtin_bit_cast(bf16x8, bfv[g][nf][ks]), \
          ACC[mf][nf], 0, 0, 0); \
    __builtin_amdgcn_s_setprio(0); \
  } while (0)

  // -------- prologue: A(0),A(1) staged; B(0) issued; drain A; read af(0) ----
  stageA(0); stageA(1);
  ISSUE_BG(0, bB[0][0], bB[0][1]);
  ISSUE_BG(1, bB[1][0], bB[1][1]);
  ISSUE_BG(2, bB[2][0], bB[2][1]);
#pragma unroll
  for (int g = 0; g < 3; ++g) { bB[g][0] += 64; bB[g][1] += 64; }
  VM(12);                        // A(0),A(1) landed; B(0) x12 in flight
  BARF();
  readA(0);

  // -------- steady tiles 0..14 (enter invariant: outstanding = [B(t) x12]) --
  for (int t = 0; t < 15; ++t) {
    stageA(t + 2);               // FIFO: [B(t)12, A(t+2)4]
    VM(12);                      // drain B(t,g0)
    MFG(0, accZ); ISSUE_BG(0, bB[0][0], bB[0][1]);
    VM(12);                      // drain B(t,g1)
    MFG(1, accR); ISSUE_BG(1, bB[1][0], bB[1][1]);
    VM(12);                      // drain B(t,g2)
    MFG(2, accH); ISSUE_BG(2, bB[2][0], bB[2][1]);
#pragma unroll
    for (int g = 0; g < 3; ++g) { bB[g][0] += 64; bB[g][1] += 64; }
    readA(t + 1);                // af for next tile (LDS parity (t+1)&1)
    LGKM0();                     // my LDS reads drained (WAR safety)
    VM(12);                      // drain A(t+2); leave [B(t+1)12]
    BARF();                      // stageA(t+3) next tile may overwrite parity
  }

  // -------- tile 15: B(16) from kerT; A(16)=embt already staged (t=14) ------
  {
    const uint16_t* kB[3][2];
#pragma unroll
    for (int g = 0; g < 3; ++g)
#pragma unroll
      for (int nf = 0; nf < 2; ++nf)
        kB[g][nf] = kerT +
            (size_t)(g * H_DIM + j0 + wn * 32 + nf * 16 + (lane & 15)) * 64 +
            (lane >> 4) * 8;
    VM(8);  MFG(0, accZ); ISSUE_BG(0, kB[0][0], kB[0][1]);
    VM(8);  MFG(1, accR); ISSUE_BG(1, kB[1][0], kB[1][1]);
    VM(8);  MFG(2, accH); ISSUE_BG(2, kB[2][0], kB[2][1]);
    readA(16);
    LGKM0();
  }
  // -------- tile 16 (input projection; gate-2 -> accX) --------
  VM(8);  MFG(0, accZ);
  VM(4);  MFG(1, accR);
  VM(0);  MFG(2, accX);

#undef ISSUE_BG
#undef MFG

  // -------- epilogue: gates in fp32, write h (f32 master + bf16) --------
#pragma unroll
  for (int nf = 0; nf < 2; ++nf) {
    int col = j0 + wn * 32 + nf * 16 + (lane & 15);
    float b_z = bias_i[col] + bias_r[col];
    float b_r = bias_i[H_DIM + col] + bias_r[H_DIM + col];
    float bih = bias_i[2 * H_DIM + col];
    float brh = bias_r[2 * H_DIM + col];
#pragma unroll
    for (int mf = 0; mf < 4; ++mf) {
#pragma unroll
      for (int q = 0; q < 4; ++q) {
        int row = r0 + wm * 64 + mf * 16 + (lane >> 4) * 4 + q;
        float z  = 1.f / (1.f + __expf(-(accZ[mf][nf][q] + b_z)));
        float rr = 1.f / (1.f + __expf(-(accR[mf][nf][q] + b_r)));
        float pre = accX[mf][nf][q] + bih + rr * (accH[mf][nf][q] + brh);
        float hc  = 2.f / (1.f + __expf(-2.f * pre)) - 1.f;   // tanh
        size_t idx = (size_t)row * H_DIM + col;
        float hold = hf[idx];
        float hnew = z * hold + (1.f - z) * hc;
        hf[idx] = hnew;
        hb_next[idx] = f2bf(hnew);
      }
    }
  }
}

// ---------------- final logits ----------------
__global__ __launch_bounds__(64) void logits_kernel(const float* __restrict__ hf,
                                                    const float* __restrict__ Wd,
                                                    const float* __restrict__ bd,
                                                    float* __restrict__ out) {
  int b = blockIdx.x;
  int l = threadIdx.x;
  float p[NLABEL];
#pragma unroll
  for (int o = 0; o < NLABEL; ++o) p[o] = 0.f;
  for (int kb = 0; kb < 16; ++kb) {
    int k = kb * 64 + l;
    float hv = hf[(size_t)b * H_DIM + k];
#pragma unroll
    for (int o = 0; o < NLABEL; ++o) p[o] += hv * Wd[k * NLABEL + o];
  }
#pragma unroll
  for (int o = 0; o < NLABEL; ++o) {
#pragma unroll
    for (int s = 32; s; s >>= 1) p[o] += __shfl_xor(p[o], s);
  }
  if (l == 0) {
#pragma unroll
    for (int o = 0; o < NLABEL; ++o) out[(size_t)b * NLABEL + o] = p[o] + bd[o];
  }
}

// ---------------- launch ----------------
extern "C" void kernel_launch(void* const* d_in, const int* in_sizes, int n_in,
                              void* d_out, int out_size, void* d_ws, size_t ws_size,
                              hipStream_t stream) {
  const int*   x          = (const int*)d_in[0];
  // d_in[1] = drop_rate (static 0, ignored)
  const float* emb_table  = (const float*)d_in[2];
  const float* kernel_w   = (const float*)d_in[3];
  const float* rec_kernel = (const float*)d_in[4];
  const float* bias_i     = (const float*)d_in[5];
  const float* bias_r     = (const float*)d_in[6];
  const float* Wd         = (const float*)d_in[7];
  const float* bd         = (const float*)d_in[8];
  float* out = (float*)d_out;

  char* ws = (char*)d_ws;
  size_t off = 0;
  auto alloc = [&](size_t bytes) {
    char* p = ws + off;
    off += (bytes + 255) & ~(size_t)255;
    return p;
  };
  float*    hf   = (float*)alloc((size_t)NB * H_DIM * 4);
  uint16_t* hb0  = (uint16_t*)alloc((size_t)NB * H_DIM * 2);
  uint16_t* hb1  = (uint16_t*)alloc((size_t)NB * H_DIM * 2);
  uint16_t* recT = (uint16_t*)alloc((size_t)G3 * H_DIM * 2);
  uint16_t* kerT = (uint16_t*)alloc((size_t)G3 * 64 * 2);
  uint16_t* embt = (uint16_t*)alloc((size_t)TSTEPS * NB * 64 * 2);
  if (off > ws_size) return;  // insufficient workspace -> fail loudly

  hipMemsetAsync(hf, 0, (size_t)NB * H_DIM * 4, stream);
  hipMemsetAsync(hb0, 0, (size_t)NB * H_DIM * 2, stream);

  prep_recT<<<dim3(G3 / 64, H_DIM / 64), 256, 0, stream>>>(rec_kernel, recT);
  prep_kerT<<<G3 / 4, 256, 0, stream>>>(kernel_w, kerT);
  prep_embt<<<TSTEPS * NB * 32 / 256, 256, 0, stream>>>(x, emb_table, embt);

  uint16_t* hb[2] = {hb0, hb1};
  for (int t = 0; t < TSTEPS; ++t) {
    gru_step_kernel<<<512, 256, 0, stream>>>(
        hb[t & 1], hf, hb[(t + 1) & 1], recT, kerT,
        embt + (size_t)t * NB * 64, bias_i, bias_r);
  }
  logits_kernel<<<NB, 64, 0, stream>>>(hf, Wd, bd, out);
}

// Round 9
// 3151.077 us; speedup vs baseline: 1.8535x; 1.8535x over previous
//
#include <hip/hip_runtime.h>
#include <stdint.h>

#define H_DIM   1024
#define G3      3072
#define EMB     50
#define TSTEPS  100
#define NB      4096
#define NLABEL  15

typedef __bf16 bf16x8 __attribute__((ext_vector_type(8)));
typedef float  f32x4  __attribute__((ext_vector_type(4)));
typedef int    i32x4  __attribute__((ext_vector_type(4)));

__device__ inline uint16_t f2bf(float f) {
  uint32_t u = __builtin_bit_cast(uint32_t, f);
  u += 0x7FFFu + ((u >> 16) & 1u);   // round-to-nearest-even
  return (uint16_t)(u >> 16);
}

__device__ inline void gld16(const void* g, void* l) {
  __builtin_amdgcn_global_load_lds(
      (const __attribute__((address_space(1))) uint32_t*)g,
      (__attribute__((address_space(3))) uint32_t*)l, 16, 0, 0);
}

// counted vmcnt + sched fence (rule #18: MFMA can hoist past bare asm waits)
#define VM(n) do { asm volatile("s_waitcnt vmcnt(" #n ")" ::: "memory"); \
                   __builtin_amdgcn_sched_barrier(0); } while (0)
#define LGKM0() do { asm volatile("s_waitcnt lgkmcnt(0)" ::: "memory"); \
                     __builtin_amdgcn_sched_barrier(0); } while (0)
#define BARF() do { __builtin_amdgcn_s_barrier(); \
                    asm volatile("" ::: "memory"); } while (0)
// async global->reg 16B load at immediate byte offset
#define GLDB(dst, addr, OFF) \
  asm volatile("global_load_dwordx4 %0, %1, off offset:" OFF \
               : "=&v"(dst) : "v"(addr) : "memory")

// ---------------- prep kernels ----------------

__global__ __launch_bounds__(256) void prep_recT(const float* __restrict__ rec,
                                                 uint16_t* __restrict__ recT) {
  __shared__ uint16_t st[64][72];
  const int n0 = blockIdx.x * 64;
  const int k0 = blockIdx.y * 64;
  const int tid = threadIdx.x;
#pragma unroll
  for (int i = 0; i < 16; ++i) {
    int idx = tid + i * 256;
    int r = idx >> 6;
    int c = idx & 63;
    st[c][r] = f2bf(rec[(size_t)(k0 + r) * G3 + n0 + c]);
  }
  __syncthreads();
#pragma unroll
  for (int i = 0; i < 16; ++i) {
    int idx = tid + i * 256;
    int r = idx >> 6;
    int c = idx & 63;
    recT[(size_t)(n0 + r) * H_DIM + k0 + c] = st[r][c];
  }
}

__global__ __launch_bounds__(256) void prep_kerT(const float* __restrict__ ker,
                                                 uint16_t* __restrict__ kerT) {
  int n = blockIdx.x * 4 + (threadIdx.x >> 6);
  int k = threadIdx.x & 63;
  float v = (k < EMB) ? ker[(size_t)k * G3 + n] : 0.f;
  kerT[(size_t)n * 64 + k] = f2bf(v);
}

// Bpk[colblk16][kt17][g3][wn2][nf2][ks2][lane64][e8] bf16 — MFMA-fragment
// order, so a wave's 4 B-loads per gate are contiguous 1KB at offsets
// 0/1024/2048/3072. kt=16 is the input-projection tile (from kerT).
__global__ __launch_bounds__(256) void prep_pack(const uint16_t* __restrict__ recT,
                                                 const uint16_t* __restrict__ kerT,
                                                 uint16_t* __restrict__ Bpk) {
  int cid = blockIdx.x * 256 + threadIdx.x;   // 16B chunk id (417792 total)
  int lane = cid & 63;
  int r = cid >> 6;
  int ks = r & 1; r >>= 1;
  int nf = r & 1; r >>= 1;
  int wn = r & 1; r >>= 1;
  int g  = r % 3; r /= 3;
  int kt = r % 17;
  int colblk = r / 17;
  int n  = g * H_DIM + colblk * 64 + wn * 32 + nf * 16 + (lane & 15);
  int kk = ks * 32 + (lane >> 4) * 8;
  const uint16_t* src = (kt < 16) ? recT + (size_t)n * H_DIM + kt * 64 + kk
                                  : kerT + (size_t)n * 64 + kk;
  *reinterpret_cast<i32x4*>(Bpk + (size_t)cid * 8) =
      *reinterpret_cast<const i32x4*>(src);
}

__global__ __launch_bounds__(256) void prep_embt(const int* __restrict__ x,
                                                 const float* __restrict__ tab,
                                                 uint16_t* __restrict__ embt) {
  int idx = blockIdx.x * 256 + threadIdx.x;
  int g = idx >> 5;
  int p = idx & 31;
  int t = g >> 12;
  int b = g & 4095;
  int row = x[b * TSTEPS + t];
  float2 v;
  if (p < 25) v = *reinterpret_cast<const float2*>(tab + (size_t)row * EMB + 2 * p);
  else { v.x = 0.f; v.y = 0.f; }
  uint32_t packed = (uint32_t)f2bf(v.x) | ((uint32_t)f2bf(v.y) << 16);
  *reinterpret_cast<uint32_t*>(embt + (size_t)g * 64 + 2 * p) = packed;
}

// ---------------- fused GRU step ----------------
// grid 512 (2 blocks/CU), block 256 (4 waves, 2x2). Tile: 128 rows x 64 cols,
// 3 gates. B-frags: DIRECT global->VGPR from fragment-packed Bpk (coalesced
// 1KB dwordx4, counted vmcnt). A: gld16->LDS (32 KB, XOR-swizzled), ONE
// barrier per K-tile.
__global__ __launch_bounds__(256, 2) void gru_step_kernel(
    const uint16_t* __restrict__ hb_prev,   // [4096][1024] bf16
    float* __restrict__ hf,                 // [4096][1024] f32 (in-place)
    uint16_t* __restrict__ hb_next,         // [4096][1024] bf16
    const uint16_t* __restrict__ Bpk,       // packed B (see prep_pack)
    const uint16_t* __restrict__ embt,      // [4096][64]   bf16 (this step)
    const float* __restrict__ bias_i,       // [3072]
    const float* __restrict__ bias_r) {     // [3072]
  __shared__ __align__(16) uint16_t sA2[2][128 * 64];     // 32 KB

  const int tid  = threadIdx.x;
  const int lane = tid & 63;
  const int wid  = tid >> 6;     // 0..3
  const int wm   = wid >> 1;     // wave row 0..1 (64 rows each)
  const int wn   = wid & 1;      // wave col 0..1 (32 cols each)
  const int bid  = blockIdx.x;
  // XCD remap: xk = bid%8 -> XCD; each XCD: 8 rowblks x 8 colblks
  const int xk = bid & 7, slot = bid >> 3;          // slot 0..63
  const int rowblk = (xk >> 1) * 8 + (slot >> 3);   // 0..31
  const int colblk = (xk & 1) * 8 + (slot & 7);     // 0..15
  const int r0 = rowblk * 128;
  const int j0 = colblk * 64;

  const int swz8 = 8 * ((lane & 7) ^ (lane >> 3));

  bf16x8 af[4][2];               // A-frags (single-buffered)
  i32x4  bfv[3][2][2];           // B-frags [gate][nf][ks] (single-buffered)
  f32x4 accZ[4][2], accR[4][2], accH[4][2], accX[4][2];
#pragma unroll
  for (int m = 0; m < 4; ++m)
#pragma unroll
    for (int n = 0; n < 2; ++n) {
      accZ[m][n] = (f32x4){0.f, 0.f, 0.f, 0.f};
      accR[m][n] = (f32x4){0.f, 0.f, 0.f, 0.f};
      accH[m][n] = (f32x4){0.f, 0.f, 0.f, 0.f};
      accX[m][n] = (f32x4){0.f, 0.f, 0.f, 0.f};
    }

  // Packed-B wave pointers, one per gate; advance 24576 B per K-tile.
  // elem strides: kt=12288, g=4096, wn=2048, nf=1024, ks=512, lane=8.
  const uint16_t* pB[3];
#pragma unroll
  for (int g = 0; g < 3; ++g)
    pB[g] = Bpk + (size_t)colblk * 17 * 12288 + g * 4096 + wn * 2048 + lane * 8;

  // stage A-tile for tile t (4 gld16/thread, 16 KB)
  auto stageA = [&](int t) {
    const int abuf = t & 1;
#pragma unroll
    for (int i = 0; i < 4; ++i) {
      int chunk = wid * 4 + i;                // 0..15
      int row = chunk * 8 + (lane >> 3);
      const uint16_t* src = (t < 16)
          ? hb_prev + (size_t)(r0 + row) * H_DIM + t * 64 + swz8
          : embt + (size_t)(r0 + row) * 64 + swz8;
      gld16(src, &sA2[abuf][(chunk * 64 + lane) * 8]);
    }
  };
  // read A fragments for tile t (8 ds_read_b128)
  auto readA = [&](int t) {
    const int abuf = t & 1;
#pragma unroll
    for (int ks = 0; ks < 2; ++ks) {
      const int colswz = (ks * 32 + (lane >> 4) * 8) ^ ((lane & 7) << 3);
#pragma unroll
      for (int mf = 0; mf < 4; ++mf)
        af[mf][ks] = *reinterpret_cast<const bf16x8*>(
            &sA2[abuf][(wm * 64 + mf * 16 + (lane & 15)) * 64 + colswz]);
    }
  };

// issue 4 coalesced 1KB B-loads of gate g (FIFO: nf0ks0,nf0ks1,nf1ks0,nf1ks1)
#define ISSUE_BG(g) do { \
    GLDB(bfv[g][0][0], pB[g], "0");    GLDB(bfv[g][0][1], pB[g], "1024"); \
    GLDB(bfv[g][1][0], pB[g], "2048"); GLDB(bfv[g][1][1], pB[g], "3072"); \
  } while (0)
// 16 MFMA of gate g into ACC
#define MFG(g, ACC) do { \
    __builtin_amdgcn_s_setprio(1); \
    _Pragma("unroll") for (int ks = 0; ks < 2; ++ks) \
    _Pragma("unroll") for (int nf = 0; nf < 2; ++nf) \
    _Pragma("unroll") for (int mf = 0; mf < 4; ++mf) \
      ACC[mf][nf] = __builtin_amdgcn_mfma_f32_16x16x32_bf16( \
          af[mf][ks], __builtin_bit_cast(bf16x8, bfv[g][nf][ks]), \
          ACC[mf][nf], 0, 0, 0); \
    __builtin_amdgcn_s_setprio(0); \
  } while (0)
#define ADV_B() do { _Pragma("unroll") \
    for (int g = 0; g < 3; ++g) pB[g] += 12288; } while (0)

  // -------- prologue: A(0),A(1) staged; B(0) issued; drain A; read af(0) ----
  stageA(0); stageA(1);
  ISSUE_BG(0); ISSUE_BG(1); ISSUE_BG(2);
  ADV_B();                       // -> kt=1
  VM(12);                        // A(0),A(1) landed; B(0) x12 in flight
  BARF();
  readA(0);

  // -------- steady tiles 0..14 (enter invariant: outstanding = [B(t) x12]) --
  for (int t = 0; t < 15; ++t) {
    stageA(t + 2);               // FIFO: [B(t)12, A(t+2)4]
    VM(12);                      // drain B(t,g0)
    MFG(0, accZ); ISSUE_BG(0);
    VM(12);                      // drain B(t,g1)
    MFG(1, accR); ISSUE_BG(1);
    VM(12);                      // drain B(t,g2)
    MFG(2, accH); ISSUE_BG(2);
    ADV_B();
    readA(t + 1);                // af for next tile (LDS parity (t+1)&1)
    LGKM0();                     // my LDS reads drained (WAR safety)
    VM(12);                      // drain A(t+2); leave [B(t+1)12]
    BARF();                      // next tile's stageA may overwrite parity
  }

  // -------- tile 15 (pB now at kt=16 entries after final ADV_B) ------------
  VM(8);  MFG(0, accZ); ISSUE_BG(0);
  VM(8);  MFG(1, accR); ISSUE_BG(1);
  VM(8);  MFG(2, accH); ISSUE_BG(2);
  readA(16);                     // A(16)=embt staged at t=14
  LGKM0();
  // -------- tile 16 (input projection; gate-2 -> accX) --------
  VM(8);  MFG(0, accZ);
  VM(4);  MFG(1, accR);
  VM(0);  MFG(2, accX);

#undef ISSUE_BG
#undef MFG
#undef ADV_B

  // -------- epilogue: gates in fp32, write h (f32 master + bf16) --------
#pragma unroll
  for (int nf = 0; nf < 2; ++nf) {
    int col = j0 + wn * 32 + nf * 16 + (lane & 15);
    float b_z = bias_i[col] + bias_r[col];
    float b_r = bias_i[H_DIM + col] + bias_r[H_DIM + col];
    float bih = bias_i[2 * H_DIM + col];
    float brh = bias_r[2 * H_DIM + col];
#pragma unroll
    for (int mf = 0; mf < 4; ++mf) {
#pragma unroll
      for (int q = 0; q < 4; ++q) {
        int row = r0 + wm * 64 + mf * 16 + (lane >> 4) * 4 + q;
        float z  = 1.f / (1.f + __expf(-(accZ[mf][nf][q] + b_z)));
        float rr = 1.f / (1.f + __expf(-(accR[mf][nf][q] + b_r)));
        float pre = accX[mf][nf][q] + bih + rr * (accH[mf][nf][q] + brh);
        float hc  = 2.f / (1.f + __expf(-2.f * pre)) - 1.f;   // tanh
        size_t idx = (size_t)row * H_DIM + col;
        float hold = hf[idx];
        float hnew = z * hold + (1.f - z) * hc;
        hf[idx] = hnew;
        hb_next[idx] = f2bf(hnew);
      }
    }
  }
}

// ---------------- final logits ----------------
__global__ __launch_bounds__(64) void logits_kernel(const float* __restrict__ hf,
                                                    const float* __restrict__ Wd,
                                                    const float* __restrict__ bd,
                                                    float* __restrict__ out) {
  int b = blockIdx.x;
  int l = threadIdx.x;
  float p[NLABEL];
#pragma unroll
  for (int o = 0; o < NLABEL; ++o) p[o] = 0.f;
  for (int kb = 0; kb < 16; ++kb) {
    int k = kb * 64 + l;
    float hv = hf[(size_t)b * H_DIM + k];
#pragma unroll
    for (int o = 0; o < NLABEL; ++o) p[o] += hv * Wd[k * NLABEL + o];
  }
#pragma unroll
  for (int o = 0; o < NLABEL; ++o) {
#pragma unroll
    for (int s = 32; s; s >>= 1) p[o] += __shfl_xor(p[o], s);
  }
  if (l == 0) {
#pragma unroll
    for (int o = 0; o < NLABEL; ++o) out[(size_t)b * NLABEL + o] = p[o] + bd[o];
  }
}

// ---------------- launch ----------------
extern "C" void kernel_launch(void* const* d_in, const int* in_sizes, int n_in,
                              void* d_out, int out_size, void* d_ws, size_t ws_size,
                              hipStream_t stream) {
  const int*   x          = (const int*)d_in[0];
  // d_in[1] = drop_rate (static 0, ignored)
  const float* emb_table  = (const float*)d_in[2];
  const float* kernel_w   = (const float*)d_in[3];
  const float* rec_kernel = (const float*)d_in[4];
  const float* bias_i     = (const float*)d_in[5];
  const float* bias_r     = (const float*)d_in[6];
  const float* Wd         = (const float*)d_in[7];
  const float* bd         = (const float*)d_in[8];
  float* out = (float*)d_out;

  char* ws = (char*)d_ws;
  size_t off = 0;
  auto alloc = [&](size_t bytes) {
    char* p = ws + off;
    off += (bytes + 255) & ~(size_t)255;
    return p;
  };
  float*    hf   = (float*)alloc((size_t)NB * H_DIM * 4);
  uint16_t* hb0  = (uint16_t*)alloc((size_t)NB * H_DIM * 2);
  uint16_t* hb1  = (uint16_t*)alloc((size_t)NB * H_DIM * 2);
  uint16_t* recT = (uint16_t*)alloc((size_t)G3 * H_DIM * 2);
  uint16_t* kerT = (uint16_t*)alloc((size_t)G3 * 64 * 2);
  uint16_t* embt = (uint16_t*)alloc((size_t)TSTEPS * NB * 64 * 2);
  uint16_t* Bpk  = (uint16_t*)alloc((size_t)16 * 17 * 12288 * 2);
  if (off > ws_size) return;  // insufficient workspace -> fail loudly

  hipMemsetAsync(hf, 0, (size_t)NB * H_DIM * 4, stream);
  hipMemsetAsync(hb0, 0, (size_t)NB * H_DIM * 2, stream);

  prep_recT<<<dim3(G3 / 64, H_DIM / 64), 256, 0, stream>>>(rec_kernel, recT);
  prep_kerT<<<G3 / 4, 256, 0, stream>>>(kernel_w, kerT);
  prep_pack<<<1632, 256, 0, stream>>>(recT, kerT, Bpk);
  prep_embt<<<TSTEPS * NB * 32 / 256, 256, 0, stream>>>(x, emb_table, embt);

  uint16_t* hb[2] = {hb0, hb1};
  for (int t = 0; t < TSTEPS; ++t) {
    gru_step_kernel<<<512, 256, 0, stream>>>(
        hb[t & 1], hf, hb[(t + 1) & 1], Bpk,
        embt + (size_t)t * NB * 64, bias_i, bias_r);
  }
  logits_kernel<<<NB, 64, 0, stream>>>(hf, Wd, bd, out);
}